// Round 20
// baseline (904.111 us; speedup 1.0000x reference)
//
#include <hip/hip_runtime.h>
#include <cstdint>
#include <cstddef>

typedef float f32x4 __attribute__((ext_vector_type(4)));
typedef float f32x16 __attribute__((ext_vector_type(16)));
typedef int i32x4 __attribute__((ext_vector_type(4)));
typedef int i32x8 __attribute__((ext_vector_type(8)));
typedef unsigned char u8;
typedef unsigned short u16;
typedef u16 u16x8 __attribute__((ext_vector_type(8)));
typedef unsigned int u32;
typedef u32 u32x4 __attribute__((ext_vector_type(4)));

// ---------------- fp8 e4m3fn (OCP) conversion, RNE ----------------
#if defined(__has_builtin)
#if __has_builtin(__builtin_amdgcn_cvt_pk_fp8_f32)
#define HAVE_HW_FP8 1
#endif
#endif

__device__ __forceinline__ u8 f32_to_e4m3_sw(float x) {
  unsigned s = (__float_as_uint(x) >> 24) & 0x80;
  float ax = fabsf(x);
  if (!(ax > 0.0f)) return (u8)s;
  if (ax >= 448.0f) return (u8)(s | 0x7e);
  if (ax < 0.015625f) {            // subnormal, step 2^-9
    int m = (int)rintf(ax * 512.0f);
    if (m >= 8) return (u8)(s | 0x08);
    return (u8)(s | m);
  }
  int e = ilogbf(ax);
  int m = (int)rintf(ldexpf(ax, 3 - e));
  if (m == 16) { ++e; m = 8; }
  return (u8)(s | ((e + 7) << 3) | (m - 8));
}

__device__ __forceinline__ unsigned cvt4_fp8(float a, float b, float c, float d) {
#ifdef HAVE_HW_FP8
  int lo = __builtin_amdgcn_cvt_pk_fp8_f32(a, b, 0, false);
  return (unsigned)__builtin_amdgcn_cvt_pk_fp8_f32(c, d, lo, true);
#else
  return (unsigned)f32_to_e4m3_sw(a) | ((unsigned)f32_to_e4m3_sw(b) << 8) |
         ((unsigned)f32_to_e4m3_sw(c) << 16) | ((unsigned)f32_to_e4m3_sw(d) << 24);
#endif
}

__device__ __forceinline__ float clamp448(float x) {
  return fminf(fmaxf(x, -448.f), 448.f);
}

__device__ __forceinline__ u16 f32_to_bf16(float x) {  // RNE
  unsigned u = __float_as_uint(x);
  return (u16)((u + 0x7FFFu + ((u >> 16) & 1u)) >> 16);
}

// ---------------- FUSED amax over 4 tensors (segmented grid) ----------------
__global__ __launch_bounds__(256) void amax4_kernel(const float* __restrict__ x,
                                                    const float* __restrict__ w1,
                                                    const float* __restrict__ v1,
                                                    const float* __restrict__ w2,
                                                    unsigned* __restrict__ out) {
  const size_t nX = (size_t)4096 * 4096 / 4;
  const size_t nW = (size_t)10752 * 4096 / 4;
  int b = (int)blockIdx.x;
  const f32x4* p;
  size_t n4;
  int slot, b0, nb;
  if (b < 232)       { p = (const f32x4*)x;  n4 = nX; slot = 0; b0 = 0;    nb = 232; }
  else if (b < 840)  { p = (const f32x4*)w1; n4 = nW; slot = 1; b0 = 232;  nb = 608; }
  else if (b < 1448) { p = (const f32x4*)v1; n4 = nW; slot = 2; b0 = 840;  nb = 608; }
  else               { p = (const f32x4*)w2; n4 = nW; slot = 3; b0 = 1448; nb = 600; }
  float m = 0.0f;
  size_t stride = (size_t)nb * 256;
  for (size_t i = (size_t)(b - b0) * 256 + threadIdx.x; i < n4; i += stride) {
    f32x4 v = p[i];
    m = fmaxf(m, fmaxf(fmaxf(fabsf(v[0]), fabsf(v[1])), fmaxf(fabsf(v[2]), fabsf(v[3]))));
  }
#pragma unroll
  for (int off = 32; off > 0; off >>= 1) m = fmaxf(m, __shfl_down(m, off));
  __shared__ float red[4];
  int lane = threadIdx.x & 63, wid = threadIdx.x >> 6;
  if (lane == 0) red[wid] = m;
  __syncthreads();
  if (threadIdx.x == 0) {
    float v = fmaxf(fmaxf(red[0], red[1]), fmaxf(red[2], red[3]));
    atomicMax(out + slot, __float_as_uint(v));
  }
}

// ---------------- generic pack-quantize f32 [R][K] -> fp8 Pk[K/32][R][32] ----------------
// thread c: kb = c / R, m = c % R. Read 128B contiguous; writes: consecutive
// threads (same kb, consecutive m) -> contiguous 32B chunks, coalesced.
__global__ __launch_bounds__(256) void pack_f32R_kernel(const float* __restrict__ src,
                                                        u8* __restrict__ dst,
                                                        const unsigned* __restrict__ amax_bits,
                                                        int R, int K) {
  float amax = __uint_as_float(*amax_bits);
  float scale = 448.0f / fmaxf(amax, 1e-12f);
  int c = (int)blockIdx.x * 256 + (int)threadIdx.x;
  int kb = c / R;
  int m = c - kb * R;
  const f32x4* s = (const f32x4*)(src + (size_t)m * K + kb * 32);
  unsigned w[8];
#pragma unroll
  for (int j = 0; j < 8; ++j) {
    f32x4 v = s[j];
    w[j] = cvt4_fp8(clamp448(v[0] * scale), clamp448(v[1] * scale),
                    clamp448(v[2] * scale), clamp448(v[3] * scale));
  }
  u32x4* d = (u32x4*)(dst + ((size_t)kb * R + m) * 32);
  d[0] = u32x4{w[0], w[1], w[2], w[3]};
  d[1] = u32x4{w[4], w[5], w[6], w[7]};
}

// ---------------- pack-quantize bf16 [4096][K] -> fp8 Pk[K/32][4096][32] ----------------
__global__ __launch_bounds__(256) void pack_bf16_kernel(const u16* __restrict__ src,
                                                        u8* __restrict__ dst,
                                                        const unsigned* __restrict__ amax_bits,
                                                        int K) {
  float amax = __uint_as_float(*amax_bits);
  float scale = 448.0f / fmaxf(amax, 1e-12f);
  int c = (int)blockIdx.x * 256 + (int)threadIdx.x;
  int m = c & 4095;
  int kb = c >> 12;
  const u16x8* s = (const u16x8*)(src + (size_t)m * K + kb * 32);
  unsigned w[8];
#pragma unroll
  for (int j = 0; j < 4; ++j) {
    u16x8 v = s[j];
    float f0 = __uint_as_float((unsigned)v[0] << 16) * scale;
    float f1 = __uint_as_float((unsigned)v[1] << 16) * scale;
    float f2 = __uint_as_float((unsigned)v[2] << 16) * scale;
    float f3 = __uint_as_float((unsigned)v[3] << 16) * scale;
    float f4 = __uint_as_float((unsigned)v[4] << 16) * scale;
    float f5 = __uint_as_float((unsigned)v[5] << 16) * scale;
    float f6 = __uint_as_float((unsigned)v[6] << 16) * scale;
    float f7 = __uint_as_float((unsigned)v[7] << 16) * scale;
    w[2 * j]     = cvt4_fp8(clamp448(f0), clamp448(f1), clamp448(f2), clamp448(f3));
    w[2 * j + 1] = cvt4_fp8(clamp448(f4), clamp448(f5), clamp448(f6), clamp448(f7));
  }
  u32x4* d = (u32x4*)(dst + ((size_t)kb * 4096 + m) * 32);
  d[0] = u32x4{w[0], w[1], w[2], w[3]};
  d[1] = u32x4{w[4], w[5], w[6], w[7]};
}

// ---------------- transpose + pack-quantize: src [R][C] f32 -> Pk[R/32][C][32] ----------------
// dst[((k>>5)*C + n)*32 + (k&31)] = q(src[k][n]);  k over R (contraction), n over C.
__global__ __launch_bounds__(256) void packT_kernel(const float* __restrict__ src,
                                                    u8* __restrict__ dst,
                                                    const unsigned* __restrict__ amax_bits,
                                                    int R, int C) {
  __shared__ float t[64][65];
  float amax = __uint_as_float(*amax_bits);
  float scale = 448.0f / fmaxf(amax, 1e-12f);
  int nbr = R >> 6;
  int br = (int)blockIdx.x % nbr, bc = (int)blockIdx.x / nbr;
  int r0 = br * 64, c0 = bc * 64;
  int tid = threadIdx.x;
  int lc = tid & 63, lr = tid >> 6;
#pragma unroll
  for (int i = 0; i < 16; ++i)
    t[lr + i * 4][lc] = src[(size_t)(r0 + lr + i * 4) * C + c0 + lc];
  __syncthreads();
  int qd = tid & 15, xbase = tid >> 4;
#pragma unroll
  for (int i = 0; i < 4; ++i) {
    int x = xbase + 16 * i;           // n within tile
    int n = c0 + x;
    int k0 = r0 + 4 * qd;             // 4 consecutive k, within one 32-block
    float v0 = clamp448(t[4 * qd + 0][x] * scale);
    float v1 = clamp448(t[4 * qd + 1][x] * scale);
    float v2 = clamp448(t[4 * qd + 2][x] * scale);
    float v3 = clamp448(t[4 * qd + 3][x] * scale);
    size_t addr = ((size_t)(k0 >> 5) * C + n) * 32 + (k0 & 31);
    *(unsigned*)(dst + addr) = cvt4_fp8(v0, v1, v2, v3);
  }
}

// Load a 32B packed fragment straight from global (coalesced: consecutive
// lanes read consecutive 32B chunks -> one 1KB segment per 32-lane group).
__device__ __forceinline__ i32x8 ld_pk(const u8* p) {
  i32x8 f;
  f.lo = *(const i32x4*)p;
  f.hi = *(const i32x4*)(p + 16);
  return f;
}

#define MFMA_MX(a, b, c) \
  __builtin_amdgcn_mfma_scale_f32_32x32x64_f8f6f4((a), (b), (c), 0, 0, 0, 0x7F7F7F7F, 0, 0x7F7F7F7F)

// ---------------- GEMM1: gate/up fused, MX-fp8, BM=256 BN=64, 4 waves ----------------
// LDS-FREE, BARRIER-FREE (r19 conclusion: 8 structural levers all pinned at
// ~37% MfmaUtil; the invariant was the per-K-step block barrier convoy).
// All operands pre-packed in fragment order -> every load is a coalesced
// 32B/lane stream from L2 (bn-major keeps slices hot). Each wave free-runs:
// prefetch t+1 into regs, 8-MFMA cluster on t; compiler-inserted waits only.
// No cross-wave communication until the epilogue amax reduction.
__global__ __launch_bounds__(256, 2) void gemm1_gateup(
    const u8* __restrict__ Apk, const u8* __restrict__ Wpk, const u8* __restrict__ Vpk,
    const unsigned* __restrict__ scal, u16* __restrict__ inter,
    unsigned* __restrict__ amax_mid, int M, int N, int K) {
  __shared__ float red[4];
  int tid = threadIdx.x;
  int lane = tid & 63, wid = tid >> 6;
  int wm = wid >> 1, wn = wid & 1;  // 2M x 2N waves, per-wave 128x32 dual

  int bid = (int)blockIdx.x;
  int bm = bid & 15;                // M/256 == 16; bn-major (L2/L3 residency)
  int bn = bid >> 4;                // F/64 == 168

  int rfrag = lane & 31;
  int h = lane >> 5;
  int arow = bm * 256 + wm * 128 + rfrag;   // 4 frags at +0/+32/+64/+96
  int nrow = bn * 64 + wn * 32 + rfrag;     // W/V row

  const size_t aStep = (size_t)64 * M;      // bytes per K-step in packed layout
  const size_t bStep = (size_t)64 * N;
  const u8* aP = Apk + 32 * ((size_t)M * h + arow);
  const u8* wP = Wpk + 32 * ((size_t)N * h + nrow);
  const u8* vP = Vpk + 32 * ((size_t)N * h + nrow);

  f32x16 g0 = (f32x16)(0.f), g1 = (f32x16)(0.f), g2 = (f32x16)(0.f), g3 = (f32x16)(0.f);
  f32x16 u0 = (f32x16)(0.f), u1 = (f32x16)(0.f), u2 = (f32x16)(0.f), u3 = (f32x16)(0.f);

  int NT = K >> 6;
  i32x8 ac0 = ld_pk(aP);
  i32x8 ac1 = ld_pk(aP + 1024);
  i32x8 ac2 = ld_pk(aP + 2048);
  i32x8 ac3 = ld_pk(aP + 3072);
  i32x8 wc = ld_pk(wP);
  i32x8 vc = ld_pk(vP);

  for (int t = 0; t < NT; ++t) {
    i32x8 an0 = ac0, an1 = ac1, an2 = ac2, an3 = ac3, wn_ = wc, vn_ = vc;
    if (t + 1 < NT) {               // register prefetch for t+1 (own-wave)
      const u8* ap = aP + (size_t)(t + 1) * aStep;
      an0 = ld_pk(ap);
      an1 = ld_pk(ap + 1024);
      an2 = ld_pk(ap + 2048);
      an3 = ld_pk(ap + 3072);
      wn_ = ld_pk(wP + (size_t)(t + 1) * bStep);
      vn_ = ld_pk(vP + (size_t)(t + 1) * bStep);
    }
    __builtin_amdgcn_s_setprio(1);
    g0 = MFMA_MX(ac0, wc, g0);
    g1 = MFMA_MX(ac1, wc, g1);
    g2 = MFMA_MX(ac2, wc, g2);
    g3 = MFMA_MX(ac3, wc, g3);
    u0 = MFMA_MX(ac0, vc, u0);
    u1 = MFMA_MX(ac1, vc, u1);
    u2 = MFMA_MX(ac2, vc, u2);
    u3 = MFMA_MX(ac3, vc, u3);
    __builtin_amdgcn_s_setprio(0);
    ac0 = an0; ac1 = an1; ac2 = an2; ac3 = an3;
    wc = wn_; vc = vn_;
  }

  float ax = __uint_as_float(scal[0]);
  float aw = __uint_as_float(scal[1]);
  float av = __uint_as_float(scal[2]);
  float inv_x = 1.0f / (448.0f / fmaxf(ax, 1e-12f));
  float inv_w = 1.0f / (448.0f / fmaxf(aw, 1e-12f));
  float inv_v = 1.0f / (448.0f / fmaxf(av, 1e-12f));
  float sg = inv_x * inv_w, su = inv_x * inv_v;

  // C/D layout 32x32: col = lane&31, row = (reg&3) + 8*(reg>>2) + 4*(lane>>5)
  int rb = bm * 256 + wm * 128 + h * 4;
  int cb = bn * 64 + wn * 32 + rfrag;
  float lmax = 0.0f;
#pragma unroll
  for (int mi = 0; mi < 4; ++mi) {
    const f32x16& gg = mi == 0 ? g0 : mi == 1 ? g1 : mi == 2 ? g2 : g3;
    const f32x16& uu = mi == 0 ? u0 : mi == 1 ? u1 : mi == 2 ? u2 : u3;
#pragma unroll
    for (int q = 0; q < 16; ++q) {
      int rr = rb + mi * 32 + (q & 3) + 8 * (q >> 2);
      float gv = gg[q] * sg;
      float uv = uu[q] * su;
      float iv = gv / (1.0f + expf(-gv)) * uv;  // silu(g)*u
      inter[(size_t)rr * N + cb] = f32_to_bf16(iv);
      lmax = fmaxf(lmax, fabsf(iv));
    }
  }
#pragma unroll
  for (int off = 32; off > 0; off >>= 1) lmax = fmaxf(lmax, __shfl_down(lmax, off));
  if (lane == 0) red[wid] = lmax;
  __syncthreads();
  if (tid == 0)
    atomicMax(amax_mid, __float_as_uint(fmaxf(fmaxf(red[0], red[1]), fmaxf(red[2], red[3]))));
}

// ---------------- GEMM2: down proj, MX-fp8, BM=256 BN=128, 4 waves ----------------
// LDS-free, barrier-free; per-wave 128x64 = 4 A-frags x 2 B-frags = 8 MFMA.
__global__ __launch_bounds__(256, 2) void gemm2_down(
    const u8* __restrict__ Apk, const u8* __restrict__ Bpk,
    const unsigned* __restrict__ amax_a, const unsigned* __restrict__ amax_b,
    float* __restrict__ out, int M, int N, int K) {
  int tid = threadIdx.x;
  int lane = tid & 63, wid = tid >> 6;
  int wm = wid >> 1, wn = wid & 1;  // per-wave 128x64

  int bid = (int)blockIdx.x;
  int bm = bid & 15;                // M/256 == 16; bn-major
  int bn = bid >> 4;                // H/128 == 32

  int rfrag = lane & 31;
  int h = lane >> 5;
  int arow = bm * 256 + wm * 128 + rfrag;
  int nrow = bn * 128 + wn * 64 + rfrag;    // B rows, frags at +0/+32

  const size_t aStep = (size_t)64 * M;
  const size_t bStep = (size_t)64 * N;
  const u8* aP = Apk + 32 * ((size_t)M * h + arow);
  const u8* bP = Bpk + 32 * ((size_t)N * h + nrow);

  f32x16 d0 = (f32x16)(0.f), d1 = (f32x16)(0.f), d2 = (f32x16)(0.f), d3 = (f32x16)(0.f);
  f32x16 e0 = (f32x16)(0.f), e1 = (f32x16)(0.f), e2 = (f32x16)(0.f), e3 = (f32x16)(0.f);

  int NT = K >> 6;
  i32x8 ac0 = ld_pk(aP);
  i32x8 ac1 = ld_pk(aP + 1024);
  i32x8 ac2 = ld_pk(aP + 2048);
  i32x8 ac3 = ld_pk(aP + 3072);
  i32x8 bc0 = ld_pk(bP);
  i32x8 bc1 = ld_pk(bP + 1024);

  for (int t = 0; t < NT; ++t) {
    i32x8 an0 = ac0, an1 = ac1, an2 = ac2, an3 = ac3, bn0 = bc0, bn1 = bc1;
    if (t + 1 < NT) {
      const u8* ap = aP + (size_t)(t + 1) * aStep;
      an0 = ld_pk(ap);
      an1 = ld_pk(ap + 1024);
      an2 = ld_pk(ap + 2048);
      an3 = ld_pk(ap + 3072);
      const u8* bp = bP + (size_t)(t + 1) * bStep;
      bn0 = ld_pk(bp);
      bn1 = ld_pk(bp + 1024);
    }
    __builtin_amdgcn_s_setprio(1);
    d0 = MFMA_MX(ac0, bc0, d0);
    d1 = MFMA_MX(ac1, bc0, d1);
    d2 = MFMA_MX(ac2, bc0, d2);
    d3 = MFMA_MX(ac3, bc0, d3);
    e0 = MFMA_MX(ac0, bc1, e0);
    e1 = MFMA_MX(ac1, bc1, e1);
    e2 = MFMA_MX(ac2, bc1, e2);
    e3 = MFMA_MX(ac3, bc1, e3);
    __builtin_amdgcn_s_setprio(0);
    ac0 = an0; ac1 = an1; ac2 = an2; ac3 = an3;
    bc0 = bn0; bc1 = bn1;
  }

  float sa = 1.0f / (448.0f / fmaxf(__uint_as_float(*amax_a), 1e-12f));
  float sb = 1.0f / (448.0f / fmaxf(__uint_as_float(*amax_b), 1e-12f));
  float sc = sa * sb;

  int rb = bm * 256 + wm * 128 + h * 4;
  int cb = bn * 128 + wn * 64 + rfrag;
#pragma unroll
  for (int mi = 0; mi < 4; ++mi) {
    const f32x16& dd = mi == 0 ? d0 : mi == 1 ? d1 : mi == 2 ? d2 : d3;
    const f32x16& ee = mi == 0 ? e0 : mi == 1 ? e1 : mi == 2 ? e2 : e3;
#pragma unroll
    for (int q = 0; q < 16; ++q) {
      int rr = rb + mi * 32 + (q & 3) + 8 * (q >> 2);
      out[(size_t)rr * N + cb] = dd[q] * sc;
      out[(size_t)rr * N + cb + 32] = ee[q] * sc;
    }
  }
}

// ---------------- host launcher ----------------
extern "C" void kernel_launch(void* const* d_in, const int* in_sizes, int n_in,
                              void* d_out, int out_size, void* d_ws, size_t ws_size,
                              hipStream_t stream) {
  const float* x  = (const float*)d_in[0];
  const float* w1 = (const float*)d_in[1];
  const float* v1 = (const float*)d_in[2];
  const float* w2 = (const float*)d_in[3];
  const int M = 4096, H = 4096, F = 10752;

  u8* ws = (u8*)d_ws;
  unsigned* scal = (unsigned*)ws;          // [0]=x [1]=w1 [2]=v1 [3]=w2 [4]=mid
  u8* xpk   = ws + 256;                    // packed [H/32][M][32]
  u8* w1pk  = xpk  + (size_t)M * H;        // packed [H/32][F][32]
  u8* v1pk  = w1pk + (size_t)F * H;        // packed [H/32][F][32]
  u8* w2pk  = v1pk + (size_t)F * H;        // packed-T [F/32][H][32]
  u8* midpk = w2pk + (size_t)F * H;        // packed [F/32][M][32]
  u16* inter = (u16*)(midpk + (size_t)M * F);  // bf16 inter

  hipMemsetAsync(scal, 0, 256, stream);
  amax4_kernel<<<2048, 256, 0, stream>>>(x, w1, v1, w2, scal);

  pack_f32R_kernel<<<(M * (H / 32)) / 256, 256, 0, stream>>>(x, xpk, scal + 0, M, H);
  pack_f32R_kernel<<<(F * (H / 32)) / 256, 256, 0, stream>>>(w1, w1pk, scal + 1, F, H);
  pack_f32R_kernel<<<(F * (H / 32)) / 256, 256, 0, stream>>>(v1, v1pk, scal + 2, F, H);
  packT_kernel<<<(F / 64) * (H / 64), 256, 0, stream>>>(w2, w2pk, scal + 3, F, H);

  gemm1_gateup<<<(M / 256) * (F / 64), 256, 0, stream>>>(xpk, w1pk, v1pk, scal, inter,
                                                         scal + 4, M, F, H);
  pack_bf16_kernel<<<(M * (F / 32)) / 256, 256, 0, stream>>>(inter, midpk, scal + 4, F);
  gemm2_down<<<(M / 256) * (H / 128), 256, 0, stream>>>(midpk, w2pk, scal + 4, scal + 3,
                                                        (float*)d_out, M, H, F);
}

// Round 21
// 888.779 us; speedup vs baseline: 1.0173x; 1.0173x over previous
//
#include <hip/hip_runtime.h>
#include <cstdint>
#include <cstddef>

typedef float f32x4 __attribute__((ext_vector_type(4)));
typedef float f32x16 __attribute__((ext_vector_type(16)));
typedef int i32x4 __attribute__((ext_vector_type(4)));
typedef int i32x8 __attribute__((ext_vector_type(8)));
typedef unsigned char u8;
typedef unsigned short u16;
typedef u16 u16x8 __attribute__((ext_vector_type(8)));
typedef unsigned int u32;
typedef u32 u32x4 __attribute__((ext_vector_type(4)));

// ---------------- async global->LDS (16B per lane, linear dest) ----------------
static __device__ __forceinline__ void gload_lds16(const void* g, void* l) {
  __builtin_amdgcn_global_load_lds(
      (__attribute__((address_space(1))) void*)(void*)g,
      (__attribute__((address_space(3))) void*)l,
      16, 0, 0);
}

// ---------------- fp8 e4m3fn (OCP) conversion, RNE ----------------
#if defined(__has_builtin)
#if __has_builtin(__builtin_amdgcn_cvt_pk_fp8_f32)
#define HAVE_HW_FP8 1
#endif
#endif

__device__ __forceinline__ u8 f32_to_e4m3_sw(float x) {
  unsigned s = (__float_as_uint(x) >> 24) & 0x80;
  float ax = fabsf(x);
  if (!(ax > 0.0f)) return (u8)s;
  if (ax >= 448.0f) return (u8)(s | 0x7e);
  if (ax < 0.015625f) {            // subnormal, step 2^-9
    int m = (int)rintf(ax * 512.0f);
    if (m >= 8) return (u8)(s | 0x08);
    return (u8)(s | m);
  }
  int e = ilogbf(ax);
  int m = (int)rintf(ldexpf(ax, 3 - e));
  if (m == 16) { ++e; m = 8; }
  return (u8)(s | ((e + 7) << 3) | (m - 8));
}

__device__ __forceinline__ unsigned cvt4_fp8(float a, float b, float c, float d) {
#ifdef HAVE_HW_FP8
  int lo = __builtin_amdgcn_cvt_pk_fp8_f32(a, b, 0, false);
  return (unsigned)__builtin_amdgcn_cvt_pk_fp8_f32(c, d, lo, true);
#else
  return (unsigned)f32_to_e4m3_sw(a) | ((unsigned)f32_to_e4m3_sw(b) << 8) |
         ((unsigned)f32_to_e4m3_sw(c) << 16) | ((unsigned)f32_to_e4m3_sw(d) << 24);
#endif
}

__device__ __forceinline__ float clamp448(float x) {
  return fminf(fmaxf(x, -448.f), 448.f);
}

__device__ __forceinline__ u16 f32_to_bf16(float x) {  // RNE
  unsigned u = __float_as_uint(x);
  return (u16)((u + 0x7FFFu + ((u >> 16) & 1u)) >> 16);
}

// ---------------- FUSED amax over 4 tensors (segmented grid) ----------------
__global__ __launch_bounds__(256) void amax4_kernel(const float* __restrict__ x,
                                                    const float* __restrict__ w1,
                                                    const float* __restrict__ v1,
                                                    const float* __restrict__ w2,
                                                    unsigned* __restrict__ out) {
  const size_t nX = (size_t)4096 * 4096 / 4;
  const size_t nW = (size_t)10752 * 4096 / 4;
  int b = (int)blockIdx.x;
  const f32x4* p;
  size_t n4;
  int slot, b0, nb;
  if (b < 232)       { p = (const f32x4*)x;  n4 = nX; slot = 0; b0 = 0;    nb = 232; }
  else if (b < 840)  { p = (const f32x4*)w1; n4 = nW; slot = 1; b0 = 232;  nb = 608; }
  else if (b < 1448) { p = (const f32x4*)v1; n4 = nW; slot = 2; b0 = 840;  nb = 608; }
  else               { p = (const f32x4*)w2; n4 = nW; slot = 3; b0 = 1448; nb = 600; }
  float m = 0.0f;
  size_t stride = (size_t)nb * 256;
  for (size_t i = (size_t)(b - b0) * 256 + threadIdx.x; i < n4; i += stride) {
    f32x4 v = p[i];
    m = fmaxf(m, fmaxf(fmaxf(fabsf(v[0]), fabsf(v[1])), fmaxf(fabsf(v[2]), fabsf(v[3]))));
  }
#pragma unroll
  for (int off = 32; off > 0; off >>= 1) m = fmaxf(m, __shfl_down(m, off));
  __shared__ float red[4];
  int lane = threadIdx.x & 63, wid = threadIdx.x >> 6;
  if (lane == 0) red[wid] = m;
  __syncthreads();
  if (threadIdx.x == 0) {
    float v = fmaxf(fmaxf(red[0], red[1]), fmaxf(red[2], red[3]));
    atomicMax(out + slot, __float_as_uint(v));
  }
}

// ---------------- FUSED quantize w1+v1 f32 -> fp8 (segmented grid) ----------------
__global__ __launch_bounds__(256) void quant2_kernel(const float* __restrict__ w1,
                                                     u8* __restrict__ w1q,
                                                     const float* __restrict__ v1,
                                                     u8* __restrict__ v1q,
                                                     const unsigned* __restrict__ scal,
                                                     size_t n8) {
  int b = (int)blockIdx.x;
  const f32x4* p;
  uint2* q;
  float amax;
  int rb;
  if (b < 1024) { p = (const f32x4*)w1; q = (uint2*)w1q; amax = __uint_as_float(scal[1]); rb = b; }
  else          { p = (const f32x4*)v1; q = (uint2*)v1q; amax = __uint_as_float(scal[2]); rb = b - 1024; }
  float scale = 448.0f / fmaxf(amax, 1e-12f);
  size_t stride = (size_t)1024 * 256;
  for (size_t i = (size_t)rb * 256 + threadIdx.x; i < n8; i += stride) {
    f32x4 a = p[2 * i], c = p[2 * i + 1];
    uint2 r;
    r.x = cvt4_fp8(clamp448(a[0] * scale), clamp448(a[1] * scale),
                   clamp448(a[2] * scale), clamp448(a[3] * scale));
    r.y = cvt4_fp8(clamp448(c[0] * scale), clamp448(c[1] * scale),
                   clamp448(c[2] * scale), clamp448(c[3] * scale));
    q[i] = r;
  }
}

// ---------------- pack-quantize f32 [4096][K] -> fp8 Apk[K/32][4096][32] ----------------
__global__ __launch_bounds__(256) void pack_f32_kernel(const float* __restrict__ src,
                                                       u8* __restrict__ dst,
                                                       const unsigned* __restrict__ amax_bits,
                                                       int K) {
  float amax = __uint_as_float(*amax_bits);
  float scale = 448.0f / fmaxf(amax, 1e-12f);
  int c = (int)blockIdx.x * 256 + (int)threadIdx.x;
  int m = c & 4095;
  int kb = c >> 12;
  const f32x4* s = (const f32x4*)(src + (size_t)m * K + kb * 32);
  unsigned w[8];
#pragma unroll
  for (int j = 0; j < 8; ++j) {
    f32x4 v = s[j];
    w[j] = cvt4_fp8(clamp448(v[0] * scale), clamp448(v[1] * scale),
                    clamp448(v[2] * scale), clamp448(v[3] * scale));
  }
  u32x4* d = (u32x4*)(dst + ((size_t)kb * 4096 + m) * 32);
  d[0] = u32x4{w[0], w[1], w[2], w[3]};
  d[1] = u32x4{w[4], w[5], w[6], w[7]};
}

// ---------------- pack-quantize bf16 [4096][K] -> fp8 Apk[K/32][4096][32] ----------------
__global__ __launch_bounds__(256) void pack_bf16_kernel(const u16* __restrict__ src,
                                                        u8* __restrict__ dst,
                                                        const unsigned* __restrict__ amax_bits,
                                                        int K) {
  float amax = __uint_as_float(*amax_bits);
  float scale = 448.0f / fmaxf(amax, 1e-12f);
  int c = (int)blockIdx.x * 256 + (int)threadIdx.x;
  int m = c & 4095;
  int kb = c >> 12;
  const u16x8* s = (const u16x8*)(src + (size_t)m * K + kb * 32);
  unsigned w[8];
#pragma unroll
  for (int j = 0; j < 4; ++j) {
    u16x8 v = s[j];
    float f0 = __uint_as_float((unsigned)v[0] << 16) * scale;
    float f1 = __uint_as_float((unsigned)v[1] << 16) * scale;
    float f2 = __uint_as_float((unsigned)v[2] << 16) * scale;
    float f3 = __uint_as_float((unsigned)v[3] << 16) * scale;
    float f4 = __uint_as_float((unsigned)v[4] << 16) * scale;
    float f5 = __uint_as_float((unsigned)v[5] << 16) * scale;
    float f6 = __uint_as_float((unsigned)v[6] << 16) * scale;
    float f7 = __uint_as_float((unsigned)v[7] << 16) * scale;
    w[2 * j]     = cvt4_fp8(clamp448(f0), clamp448(f1), clamp448(f2), clamp448(f3));
    w[2 * j + 1] = cvt4_fp8(clamp448(f4), clamp448(f5), clamp448(f6), clamp448(f7));
  }
  u32x4* d = (u32x4*)(dst + ((size_t)kb * 4096 + m) * 32);
  d[0] = u32x4{w[0], w[1], w[2], w[3]};
  d[1] = u32x4{w[4], w[5], w[6], w[7]};
}

// ---------------- transpose + quantize: src [R][C] f32 -> dst [C][R] fp8 ----------------
__global__ __launch_bounds__(256) void quantT_kernel(const float* __restrict__ src,
                                                     u8* __restrict__ dst,
                                                     const unsigned* __restrict__ amax_bits,
                                                     int R, int C) {
  __shared__ float t[64][65];
  float amax = __uint_as_float(*amax_bits);
  float scale = 448.0f / fmaxf(amax, 1e-12f);
  int nbr = R >> 6;
  int br = (int)blockIdx.x % nbr, bc = (int)blockIdx.x / nbr;
  int r0 = br * 64, c0 = bc * 64;
  int tid = threadIdx.x;
  int lc = tid & 63, lr = tid >> 6;
#pragma unroll
  for (int i = 0; i < 16; ++i)
    t[lr + i * 4][lc] = src[(size_t)(r0 + lr + i * 4) * C + c0 + lc];
  __syncthreads();
  int qd = tid & 15, xbase = tid >> 4;
#pragma unroll
  for (int i = 0; i < 4; ++i) {
    int x = xbase + 16 * i;  // output row index (column of src tile)
    float v0 = clamp448(t[4 * qd + 0][x] * scale);
    float v1 = clamp448(t[4 * qd + 1][x] * scale);
    float v2 = clamp448(t[4 * qd + 2][x] * scale);
    float v3 = clamp448(t[4 * qd + 3][x] * scale);
    *(unsigned*)(dst + (size_t)(c0 + x) * R + r0 + 4 * qd) = cvt4_fp8(v0, v1, v2, v3);
  }
}

// ---------------- LDS address swizzle ----------------
// 16B-block XOR within 64B row, key = (row>>2)&3 (verified conflict-free
// rounds 3-20: SQ_LDS_BANK_CONFLICT == 0).
__device__ __forceinline__ int swz_key(int r) { return (r >> 2) & 3; }

__device__ __forceinline__ int swz_off32(int r, int h) {
  return r * 64 + ((((h << 1) ^ swz_key(r)) << 4));
}

// Load a 32B MX-fp8 fragment (k-half h of row r) from a swizzled [*][64] tile.
__device__ __forceinline__ i32x8 ld_frag(const u8* base, int r, int h) {
  int o = swz_off32(r, h);
  i32x8 f;
  f.lo = *(const i32x4*)(base + o);
  f.hi = *(const i32x4*)(base + (o ^ 16));
  return f;
}

// Load a 32B packed-A fragment straight from global (coalesced).
__device__ __forceinline__ i32x8 ld_a_g(const u8* p) {
  i32x8 f;
  f.lo = *(const i32x4*)p;
  f.hi = *(const i32x4*)(p + 16);
  return f;
}

#define MFMA_MX(a, b, c) \
  __builtin_amdgcn_mfma_scale_f32_32x32x64_f8f6f4((a), (b), (c), 0, 0, 0, 0x7F7F7F7F, 0, 0x7F7F7F7F)

// ---------------- GEMM1: gate/up fused, NT, MX-fp8, BM=256 BN=64, 4 waves ----------------
// FINAL (best measured, round 18: 888 us total). Tall-M geometry: per-wave
// 128x32 dual output = 4 M-frags (packed-A from global, coalesced) x 1 B-frag
// each for W and V; W/V via LDS tri-buffer; counted vmcnt(10) + B0 barrier
// (r9 race-fix: vmcnt is per-wave, barrier makes tile visibility block-wide);
// bn-major block order (r14: FETCH 1.41GB->0.39GB via L2/L3 residency);
// bf16 inter. Ten orthogonal structural levers (sync x7 incl. 0-barrier,
// occupancy, A/LDS placement, geometry) all measured 424-456us @ ~38%
// MfmaUtil — the documented m97-class structural plateau for non-8-phase
// schedules on this op.
__global__ __launch_bounds__(256, 2) void gemm1_gateup(
    const u8* __restrict__ Apk, const u8* __restrict__ Wq, const u8* __restrict__ Vq,
    const unsigned* __restrict__ scal, u16* __restrict__ inter,
    unsigned* __restrict__ amax_mid, int M, int N, int K) {
  __shared__ __align__(16) u8 lW[3][4096], lV[3][4096];
  __shared__ float red[4];
  int tid = threadIdx.x;
  int lane = tid & 63, wid = tid >> 6;
  int wm = wid >> 1, wn = wid & 1;  // 2M x 2N waves, per-wave 128x32 dual

  int bid = (int)blockIdx.x;
  int bm = bid & 15;                // M/256 == 16; bn-major (L2/L3 residency)
  int bn = bid >> 4;                // F/64 == 168

  int r0 = tid >> 2;                           // 0..63
  int kblk = ((tid & 3) ^ swz_key(r0)) << 4;   // pre-swizzled global source chunk
  const u8* wS = Wq + (size_t)(bn * 64 + r0) * K + kblk;
  const u8* vS = Vq + (size_t)(bn * 64 + r0) * K + kblk;

  f32x16 g0 = (f32x16)(0.f), g1 = (f32x16)(0.f), g2 = (f32x16)(0.f), g3 = (f32x16)(0.f);
  f32x16 u0 = (f32x16)(0.f), u1 = (f32x16)(0.f), u2 = (f32x16)(0.f), u3 = (f32x16)(0.f);

  int rfrag = lane & 31;
  int h = lane >> 5;
  int arow = wm * 128 + rfrag;      // A rows, 4 frags at +0/+32/+64/+96
  int brow = wn * 32 + rfrag;       // W/V rows 0..63

  const size_t tStride = (size_t)64 * M;
  const u8* aP = Apk + 32 * ((size_t)M * h + (size_t)(bm * 256 + arow));

  int NT = K >> 6;
  // prologue: stage W/V tiles 0,1 (1 gload each); A-frags tile 0; full drain.
  gload_lds16(wS + 0, lW[0] + tid * 16);
  gload_lds16(vS + 0, lV[0] + tid * 16);
  gload_lds16(wS + 64, lW[1] + tid * 16);
  gload_lds16(vS + 64, lV[1] + tid * 16);
  i32x8 ac0 = ld_a_g(aP);
  i32x8 ac1 = ld_a_g(aP + 1024);
  i32x8 ac2 = ld_a_g(aP + 2048);
  i32x8 ac3 = ld_a_g(aP + 3072);
  i32x8 an0 = ac0, an1 = ac1, an2 = ac2, an3 = ac3;
  asm volatile("s_waitcnt vmcnt(0)" ::: "memory");
  __builtin_amdgcn_s_barrier();

  for (int t = 0; t < NT; ++t) {
    int cur = t % 3;
    int nx = cur + 2; if (nx >= 3) nx -= 3;   // (t+2)%3
    int kt2 = (t + 2) * 64;
    bool do_stage = (t + 2) < NT;
    bool do_pref = (t + 1) < NT;
    if (do_pref) {
      asm volatile("s_waitcnt vmcnt(10)" ::: "memory");
    } else {
      asm volatile("s_waitcnt vmcnt(0)" ::: "memory");
    }
    __builtin_amdgcn_s_barrier();   // B0 (race fix)
    i32x8 w0 = ld_frag(lW[cur], brow, h);
    i32x8 v0 = ld_frag(lV[cur], brow, h);
    if (do_pref) {                  // packed-A prefetch for t+1 (own-wave regs)
      const u8* ap = aP + (size_t)(t + 1) * tStride;
      an0 = ld_a_g(ap);
      an1 = ld_a_g(ap + 1024);
      an2 = ld_a_g(ap + 2048);
      an3 = ld_a_g(ap + 3072);
    }
    if (do_stage) {
      gload_lds16(wS + kt2, lW[nx] + tid * 16);
      gload_lds16(vS + kt2, lV[nx] + tid * 16);
    }
    __builtin_amdgcn_s_barrier();   // B1
    __builtin_amdgcn_s_setprio(1);
    g0 = MFMA_MX(ac0, w0, g0);
    g1 = MFMA_MX(ac1, w0, g1);
    g2 = MFMA_MX(ac2, w0, g2);
    g3 = MFMA_MX(ac3, w0, g3);
    u0 = MFMA_MX(ac0, v0, u0);
    u1 = MFMA_MX(ac1, v0, u1);
    u2 = MFMA_MX(ac2, v0, u2);
    u3 = MFMA_MX(ac3, v0, u3);
    __builtin_amdgcn_s_setprio(0);
    ac0 = an0; ac1 = an1; ac2 = an2; ac3 = an3;
    // next iteration's B0 doubles as the trailing barrier
  }

  float ax = __uint_as_float(scal[0]);
  float aw = __uint_as_float(scal[1]);
  float av = __uint_as_float(scal[2]);
  float inv_x = 1.0f / (448.0f / fmaxf(ax, 1e-12f));
  float inv_w = 1.0f / (448.0f / fmaxf(aw, 1e-12f));
  float inv_v = 1.0f / (448.0f / fmaxf(av, 1e-12f));
  float sg = inv_x * inv_w, su = inv_x * inv_v;

  // C/D layout 32x32: col = lane&31, row = (reg&3) + 8*(reg>>2) + 4*(lane>>5)
  int rb = bm * 256 + wm * 128 + h * 4;
  int cb = bn * 64 + wn * 32 + rfrag;
  float lmax = 0.0f;
#pragma unroll
  for (int mi = 0; mi < 4; ++mi) {
    const f32x16& gg = mi == 0 ? g0 : mi == 1 ? g1 : mi == 2 ? g2 : g3;
    const f32x16& uu = mi == 0 ? u0 : mi == 1 ? u1 : mi == 2 ? u2 : u3;
#pragma unroll
    for (int q = 0; q < 16; ++q) {
      int rr = rb + mi * 32 + (q & 3) + 8 * (q >> 2);
      float gv = gg[q] * sg;
      float uv = uu[q] * su;
      float iv = gv / (1.0f + expf(-gv)) * uv;  // silu(g)*u
      inter[(size_t)rr * N + cb] = f32_to_bf16(iv);
      lmax = fmaxf(lmax, fabsf(iv));
    }
  }
#pragma unroll
  for (int off = 32; off > 0; off >>= 1) lmax = fmaxf(lmax, __shfl_down(lmax, off));
  if (lane == 0) red[wid] = lmax;
  __syncthreads();
  if (tid == 0)
    atomicMax(amax_mid, __float_as_uint(fmaxf(fmaxf(red[0], red[1]), fmaxf(red[2], red[3]))));
}

// ---------------- GEMM2: down proj, NT vs pre-transposed w2, BM=256 BN=128 ----------------
// Tall-M: per-wave 128x64 = 4 M-frags x 2 B-frags = 8 MFMA, acc 128 regs.
// Per-iter VMEM = A-pref(8) + stage(2) = 10 -> vmcnt(10); same ledger.
__global__ __launch_bounds__(256, 2) void gemm2_down(
    const u8* __restrict__ Apk, const u8* __restrict__ Bq,
    const unsigned* __restrict__ amax_a, const unsigned* __restrict__ amax_b,
    float* __restrict__ out, int M, int N, int K) {
  __shared__ __align__(16) u8 lB[3][8192];
  int tid = threadIdx.x;
  int lane = tid & 63, wid = tid >> 6;
  int wm = wid >> 1, wn = wid & 1;  // per-wave 128x64

  int bid = (int)blockIdx.x;
  int bm = bid & 15;                // M/256 == 16; bn-major
  int bn = bid >> 4;                // H/128 == 32

  int r0 = tid >> 2;
  int kblk = ((tid & 3) ^ swz_key(r0)) << 4;
  const u8* bS = Bq + (size_t)(bn * 128 + r0) * K + kblk;
  size_t rK = (size_t)64 * K;       // rows 64..127 (key period 16 -> same kblk)

  f32x16 d0 = (f32x16)(0.f), d1 = (f32x16)(0.f), d2 = (f32x16)(0.f), d3 = (f32x16)(0.f);
  f32x16 e0 = (f32x16)(0.f), e1 = (f32x16)(0.f), e2 = (f32x16)(0.f), e3 = (f32x16)(0.f);

  int rfrag = lane & 31;
  int h = lane >> 5;
  int arow = wm * 128 + rfrag;
  int brow = wn * 64 + rfrag;       // 0..127 span, frags at +0/+32

  const size_t tStride = (size_t)64 * M;
  const u8* aP = Apk + 32 * ((size_t)M * h + (size_t)(bm * 256 + arow));

  int NT = K >> 6;
  gload_lds16(bS + 0, lB[0] + tid * 16);
  gload_lds16(bS + 0 + rK, lB[0] + 4096 + tid * 16);
  gload_lds16(bS + 64, lB[1] + tid * 16);
  gload_lds16(bS + 64 + rK, lB[1] + 4096 + tid * 16);
  i32x8 ac0 = ld_a_g(aP);
  i32x8 ac1 = ld_a_g(aP + 1024);
  i32x8 ac2 = ld_a_g(aP + 2048);
  i32x8 ac3 = ld_a_g(aP + 3072);
  i32x8 an0 = ac0, an1 = ac1, an2 = ac2, an3 = ac3;
  asm volatile("s_waitcnt vmcnt(0)" ::: "memory");
  __builtin_amdgcn_s_barrier();

  for (int t = 0; t < NT; ++t) {
    int cur = t % 3;
    int nx = cur + 2; if (nx >= 3) nx -= 3;
    int kt2 = (t + 2) * 64;
    bool do_stage = (t + 2) < NT;
    bool do_pref = (t + 1) < NT;
    if (do_pref) {
      asm volatile("s_waitcnt vmcnt(10)" ::: "memory");
    } else {
      asm volatile("s_waitcnt vmcnt(0)" ::: "memory");
    }
    __builtin_amdgcn_s_barrier();   // B0 (race fix)
    i32x8 b0 = ld_frag(lB[cur], brow, h);
    i32x8 b1 = ld_frag(lB[cur], brow + 32, h);
    if (do_pref) {
      const u8* ap = aP + (size_t)(t + 1) * tStride;
      an0 = ld_a_g(ap);
      an1 = ld_a_g(ap + 1024);
      an2 = ld_a_g(ap + 2048);
      an3 = ld_a_g(ap + 3072);
    }
    if (do_stage) {
      gload_lds16(bS + kt2, lB[nx] + tid * 16);
      gload_lds16(bS + kt2 + rK, lB[nx] + 4096 + tid * 16);
    }
    __builtin_amdgcn_s_barrier();
    __builtin_amdgcn_s_setprio(1);
    d0 = MFMA_MX(ac0, b0, d0);
    d1 = MFMA_MX(ac1, b0, d1);
    d2 = MFMA_MX(ac2, b0, d2);
    d3 = MFMA_MX(ac3, b0, d3);
    e0 = MFMA_MX(ac0, b1, e0);
    e1 = MFMA_MX(ac1, b1, e1);
    e2 = MFMA_MX(ac2, b1, e2);
    e3 = MFMA_MX(ac3, b1, e3);
    __builtin_amdgcn_s_setprio(0);
    ac0 = an0; ac1 = an1; ac2 = an2; ac3 = an3;
  }

  float sa = 1.0f / (448.0f / fmaxf(__uint_as_float(*amax_a), 1e-12f));
  float sb = 1.0f / (448.0f / fmaxf(__uint_as_float(*amax_b), 1e-12f));
  float sc = sa * sb;

  int rb = bm * 256 + wm * 128 + h * 4;
  int cb = bn * 128 + wn * 64 + rfrag;
#pragma unroll
  for (int mi = 0; mi < 4; ++mi) {
    const f32x16& dd = mi == 0 ? d0 : mi == 1 ? d1 : mi == 2 ? d2 : d3;
    const f32x16& ee = mi == 0 ? e0 : mi == 1 ? e1 : mi == 2 ? e2 : e3;
#pragma unroll
    for (int q = 0; q < 16; ++q) {
      int rr = rb + mi * 32 + (q & 3) + 8 * (q >> 2);
      out[(size_t)rr * N + cb] = dd[q] * sc;
      out[(size_t)rr * N + cb + 32] = ee[q] * sc;
    }
  }
}

// ---------------- host launcher ----------------
extern "C" void kernel_launch(void* const* d_in, const int* in_sizes, int n_in,
                              void* d_out, int out_size, void* d_ws, size_t ws_size,
                              hipStream_t stream) {
  const float* x  = (const float*)d_in[0];
  const float* w1 = (const float*)d_in[1];
  const float* v1 = (const float*)d_in[2];
  const float* w2 = (const float*)d_in[3];
  const int M = 4096, H = 4096, F = 10752;

  u8* ws = (u8*)d_ws;
  unsigned* scal = (unsigned*)ws;          // [0]=x [1]=w1 [2]=v1 [3]=w2 [4]=mid
  u8* xpk  = ws + 256;                     // packed A for gemm1 [H/32][M][32]
  u8* w1q  = xpk  + (size_t)M * H;
  u8* v1q  = w1q  + (size_t)F * H;
  u8* w2qT = v1q  + (size_t)F * H;
  u8* midpk = w2qT + (size_t)F * H;        // packed A for gemm2 [F/32][M][32]
  u16* inter = (u16*)(midpk + (size_t)M * F);  // bf16 inter

  hipMemsetAsync(scal, 0, 256, stream);
  amax4_kernel<<<2048, 256, 0, stream>>>(x, w1, v1, w2, scal);

  pack_f32_kernel<<<(M * (H / 32)) / 256, 256, 0, stream>>>(x, xpk, scal + 0, H);
  quant2_kernel<<<2048, 256, 0, stream>>>(w1, w1q, v1, v1q, scal, (size_t)F * H / 8);
  quantT_kernel<<<(F / 64) * (H / 64), 256, 0, stream>>>(w2, w2qT, scal + 3, F, H);

  gemm1_gateup<<<(M / 256) * (F / 64), 256, 0, stream>>>(xpk, w1q, v1q, scal, inter,
                                                         scal + 4, M, F, H);
  pack_bf16_kernel<<<(M * (F / 32)) / 256, 256, 0, stream>>>(inter, midpk, scal + 4, F);
  gemm2_down<<<(M / 256) * (H / 128), 256, 0, stream>>>(midpk, w2qT, scal + 4, scal + 3,
                                                        (float*)d_out, M, H, F);
}